// Round 3
// baseline (337.437 us; speedup 1.0000x reference)
//
#include <hip/hip_runtime.h>
#include <hip/hip_bf16.h>

// SubjectLayers via bf16 MFMA: out[b,o,t] = sum_c W[s(b),o,c]*x[b,c,t] + bias[s(b),o]
// B=128, C=64, T=8192, S=16. fp32 in/out, bf16 matrix cores inside
// (threshold 0.117 >> expected bf16 error ~0.05).
//
// R2 design (resubmit after infra failure):
//  - no LDS, no barriers; each wave owns ALL 64 outputs and a private 256-col
//    t-range -> x loaded exactly once, W (16KB) L2-resident.
//  - mfma_f32_16x16x32_bf16; A=W tiles (4 o-tiles x 2 k-blocks) in regs.
//  - B frag: lane holds x[c = kb*32 + (lane>>4)*8 + j][t0 + (lane&15)]:
//    dword/lane loads, 64B-contiguous per 16-lane group = full cache lines.
//  - 1-step x prefetch hides HBM latency (64KB in flight per CU).

typedef __attribute__((ext_vector_type(8))) short bf16x8;
typedef __attribute__((ext_vector_type(4))) float f32x4;

namespace {
constexpr int Cdim  = 64;
constexpr int Tdim  = 8192;
constexpr int WT    = 16;     // t-steps (16 cols each) per wave -> 256 t/wave
constexpr int BLOCK = 256;    // 4 waves -> 1024 t per block
}

static __device__ __forceinline__ short f2bf(float f) {
    return (short)__builtin_bit_cast(unsigned short, __float2bfloat16(f));
}

__global__ __launch_bounds__(BLOCK, 4)
void subject_layers_mfma(const float* __restrict__ x,
                         const int*   __restrict__ subj,
                         const float* __restrict__ W,
                         const float* __restrict__ bias,
                         float*       __restrict__ out) {
    const int b    = blockIdx.y;
    const int tid  = threadIdx.x;
    const int wave = tid >> 6;
    const int lane = tid & 63;
    const int lg   = lane >> 4;   // lane group 0..3
    const int lm   = lane & 15;   // m/n index within tile
    const int s    = subj[b];

    const int t0 = (blockIdx.x * 4 + wave) * (WT * 16);

    // ---- A fragments: W[s] -> bf16, 4 o-tiles x 2 k-blocks (once per wave) ----
    // A[m][k]: m = lm, k = kb*32 + lg*8 + j  (mirrored with B so any k-perm cancels)
    bf16x8 afrag[4][2];
    const float* Wbase = W + (size_t)s * Cdim * Cdim;
    #pragma unroll
    for (int w = 0; w < 4; ++w) {
        #pragma unroll
        for (int kb = 0; kb < 2; ++kb) {
            const float* ap = Wbase + (size_t)(w * 16 + lm) * Cdim + kb * 32 + lg * 8;
            const float4 a0 = *reinterpret_cast<const float4*>(ap);
            const float4 a1 = *reinterpret_cast<const float4*>(ap + 4);
            bf16x8 f;
            f[0] = f2bf(a0.x); f[1] = f2bf(a0.y); f[2] = f2bf(a0.z); f[3] = f2bf(a0.w);
            f[4] = f2bf(a1.x); f[5] = f2bf(a1.y); f[6] = f2bf(a1.z); f[7] = f2bf(a1.w);
            afrag[w][kb] = f;
        }
    }

    // ---- bias for this lane's C-rows: row = w*16 + lg*4 + i ----
    float bv[4][4];
    const float* bb = bias + (size_t)s * Cdim;
    #pragma unroll
    for (int w = 0; w < 4; ++w)
        #pragma unroll
        for (int i = 0; i < 4; ++i)
            bv[w][i] = bb[w * 16 + lg * 4 + i];

    // per-lane bases
    const float* xb = x   + (size_t)b * Cdim * Tdim + (size_t)(lg * 8) * Tdim + t0 + lm;
    float*       ob = out + (size_t)b * Cdim * Tdim + (size_t)(lg * 4) * Tdim + t0 + lm;

    // ---- main loop over WT t-steps, 1-step x prefetch ----
    float xraw[2][8];
    #pragma unroll
    for (int kb = 0; kb < 2; ++kb)
        #pragma unroll
        for (int j = 0; j < 8; ++j)
            xraw[kb][j] = xb[(size_t)(kb * 32 + j) * Tdim];

    #pragma unroll
    for (int step = 0; step < WT; ++step) {
        float xnext[2][8];
        if (step + 1 < WT) {
            #pragma unroll
            for (int kb = 0; kb < 2; ++kb)
                #pragma unroll
                for (int j = 0; j < 8; ++j)
                    xnext[kb][j] = xb[(size_t)(kb * 32 + j) * Tdim + (step + 1) * 16];
        }

        // B frag: B[k][n]: n = lm, k = kb*32 + lg*8 + j  (mirror of A)
        bf16x8 bfrag[2];
        #pragma unroll
        for (int kb = 0; kb < 2; ++kb) {
            bf16x8 f;
            #pragma unroll
            for (int j = 0; j < 8; ++j) f[j] = f2bf(xraw[kb][j]);
            bfrag[kb] = f;
        }

        #pragma unroll
        for (int w = 0; w < 4; ++w) {
            f32x4 acc = {bv[w][0], bv[w][1], bv[w][2], bv[w][3]};
            acc = __builtin_amdgcn_mfma_f32_16x16x32_bf16(afrag[w][0], bfrag[0], acc, 0, 0, 0);
            acc = __builtin_amdgcn_mfma_f32_16x16x32_bf16(afrag[w][1], bfrag[1], acc, 0, 0, 0);
            // C/D: col = lane&15, row = (lane>>4)*4 + i  [m89-verified]
            #pragma unroll
            for (int i = 0; i < 4; ++i)
                ob[(size_t)(w * 16 + i) * Tdim + step * 16] = acc[i];
        }

        #pragma unroll
        for (int kb = 0; kb < 2; ++kb)
            #pragma unroll
            for (int j = 0; j < 8; ++j)
                xraw[kb][j] = xnext[kb][j];
    }
}

extern "C" void kernel_launch(void* const* d_in, const int* in_sizes, int n_in,
                              void* d_out, int out_size, void* d_ws, size_t ws_size,
                              hipStream_t stream) {
    const float* x    = (const float*)d_in[0];   // [B, C, T]
    const int*   subj = (const int*)  d_in[1];   // [B]
    const float* W    = (const float*)d_in[2];   // [S, C, C]
    const float* bias = (const float*)d_in[3];   // [S, C]
    float*       out  = (float*)d_out;           // [B, C, T]

    const int B = in_sizes[1];                   // 128
    dim3 grid(Tdim / (4 * WT * 16), B);          // (8, 128) = 1024 blocks
    dim3 block(BLOCK);
    hipLaunchKernelGGL(subject_layers_mfma, grid, block, 0, stream,
                       x, subj, W, bias, out);
}

// Round 4
// 119.801 us; speedup vs baseline: 2.8166x; 2.8166x over previous
//
#include <hip/hip_runtime.h>
#include <hip/hip_bf16.h>

// SubjectLayers via bf16 MFMA 32x32x16: out[b,o,t] = sum_c W[s,o,c]*x[b,c,t] + b[s,o]
// B=128, C=64, T=8192, S=16. fp32 in/out, bf16 matrix cores.
//
// R3: fix R2's 2.2x write / 1.85x fetch amplification (64B partial-line access
// from the 16x16 fragment) by switching to 32x32x16 fragments:
//  - every global load/store instruction = 2 rows x 128B FULL aligned lines
//  - still no LDS, no barriers; W frags register-resident; wave owns 64 outputs
//    x private 512-t range; 1-step x prefetch (8KB in flight per wave).

typedef __attribute__((ext_vector_type(8))) short  bf16x8;   // 4 VGPRs
typedef __attribute__((ext_vector_type(16))) float f32x16;   // 16 VGPRs

namespace {
constexpr int Cdim  = 64;
constexpr int Tdim  = 8192;
constexpr int NSTEP = 16;    // 32-wide t-steps per wave -> 512 t/wave
constexpr int BLOCK = 256;   // 4 waves -> 2048 t per block
}

static __device__ __forceinline__ short f2bf(float f) {
    return (short)__builtin_bit_cast(unsigned short, __float2bfloat16(f));
}

__global__ __launch_bounds__(BLOCK, 2)
void subject_layers_mfma32(const float* __restrict__ x,
                           const int*   __restrict__ subj,
                           const float* __restrict__ W,
                           const float* __restrict__ bias,
                           float*       __restrict__ out) {
    const int b    = blockIdx.y;
    const int tid  = threadIdx.x;
    const int wave = tid >> 6;
    const int lane = tid & 63;
    const int hi   = lane >> 5;   // 0..1
    const int ln   = lane & 31;   // m/n index within 32-tile
    const int s    = subj[b];

    const int t0 = (blockIdx.x * 4 + wave) * (NSTEP * 32);

    // ---- A fragments: W[s] -> bf16. 2 o-tiles (32 rows) x 4 k-blocks (16) ----
    // A[m][k]: m = ln, k = kb*16 + hi*8 + j   (mirrored with B -> k-perm cancels)
    bf16x8 afrag[2][4];
    const float* Wb = W + (size_t)s * Cdim * Cdim;
    #pragma unroll
    for (int ot = 0; ot < 2; ++ot) {
        #pragma unroll
        for (int kb = 0; kb < 4; ++kb) {
            const float* ap = Wb + (size_t)(ot * 32 + ln) * Cdim + kb * 16 + hi * 8;
            const float4 a0 = *reinterpret_cast<const float4*>(ap);
            const float4 a1 = *reinterpret_cast<const float4*>(ap + 4);
            bf16x8 f;
            f[0] = f2bf(a0.x); f[1] = f2bf(a0.y); f[2] = f2bf(a0.z); f[3] = f2bf(a0.w);
            f[4] = f2bf(a1.x); f[5] = f2bf(a1.y); f[6] = f2bf(a1.z); f[7] = f2bf(a1.w);
            afrag[ot][kb] = f;
        }
    }

    // ---- bias -> accumulator init vectors ----
    // C/D: col = ln, row(reg r) = (r&3) + 8*(r>>2) + 4*hi   [m74/m101-verified]
    f32x16 bini[2];
    const float* bb = bias + (size_t)s * Cdim;
    #pragma unroll
    for (int ot = 0; ot < 2; ++ot)
        #pragma unroll
        for (int r = 0; r < 16; ++r)
            bini[ot][r] = bb[ot * 32 + (r & 3) + 8 * (r >> 2) + 4 * hi];

    // per-lane bases
    const float* xb = x   + (size_t)b * Cdim * Tdim + (size_t)(hi * 8) * Tdim + t0 + ln;
    float*       ob = out + (size_t)b * Cdim * Tdim + (size_t)(hi * 4) * Tdim + t0 + ln;

    // ---- main loop: 32-t steps, 1-step x prefetch ----
    // x element for (kb,j): c = kb*16 + hi*8 + j, t = t0 + step*32 + ln
    // per load instr: 2 rows x 128B full aligned lines.
    float xr[4][8];
    #pragma unroll
    for (int kb = 0; kb < 4; ++kb)
        #pragma unroll
        for (int j = 0; j < 8; ++j)
            xr[kb][j] = xb[(size_t)(kb * 16 + j) * Tdim];

    #pragma unroll 4
    for (int step = 0; step < NSTEP; ++step) {
        float xn[4][8];
        if (step + 1 < NSTEP) {
            #pragma unroll
            for (int kb = 0; kb < 4; ++kb)
                #pragma unroll
                for (int j = 0; j < 8; ++j)
                    xn[kb][j] = xb[(size_t)(kb * 16 + j) * Tdim + (step + 1) * 32];
        }

        // B frag: B[k][n]: n = ln, k = kb*16 + hi*8 + j  (mirror of A)
        bf16x8 bfrag[4];
        #pragma unroll
        for (int kb = 0; kb < 4; ++kb) {
            bf16x8 f;
            #pragma unroll
            for (int j = 0; j < 8; ++j) f[j] = f2bf(xr[kb][j]);
            bfrag[kb] = f;
        }

        #pragma unroll
        for (int ot = 0; ot < 2; ++ot) {
            f32x16 acc = bini[ot];
            #pragma unroll
            for (int kb = 0; kb < 4; ++kb)
                acc = __builtin_amdgcn_mfma_f32_32x32x16_bf16(afrag[ot][kb], bfrag[kb], acc, 0, 0, 0);
            // store: per reg r, 2 rows x 128B full lines
            #pragma unroll
            for (int r = 0; r < 16; ++r)
                ob[(size_t)(ot * 32 + (r & 3) + 8 * (r >> 2)) * Tdim + step * 32] = acc[r];
        }

        #pragma unroll
        for (int kb = 0; kb < 4; ++kb)
            #pragma unroll
            for (int j = 0; j < 8; ++j)
                xr[kb][j] = xn[kb][j];
    }
}

extern "C" void kernel_launch(void* const* d_in, const int* in_sizes, int n_in,
                              void* d_out, int out_size, void* d_ws, size_t ws_size,
                              hipStream_t stream) {
    const float* x    = (const float*)d_in[0];   // [B, C, T]
    const int*   subj = (const int*)  d_in[1];   // [B]
    const float* W    = (const float*)d_in[2];   // [S, C, C]
    const float* bias = (const float*)d_in[3];   // [S, C]
    float*       out  = (float*)d_out;           // [B, C, T]

    const int B = in_sizes[1];                   // 128
    dim3 grid(Tdim / (4 * NSTEP * 32), B);       // (4, 128) = 512 blocks
    dim3 block(BLOCK);
    hipLaunchKernelGGL(subject_layers_mfma32, grid, block, 0, stream,
                       x, subj, W, bias, out);
}